// Round 1
// baseline (1836.210 us; speedup 1.0000x reference)
//
#include <hip/hip_runtime.h>
#include <hip/hip_bf16.h>
#include <stdint.h>

#define K_DIM 4096
#define BM 128
#define BN 128
#define BK 32
#define LDK 40  // padded LDS row stride (elements): 80B rows keep 16B alignment, ~2-way banks

typedef __bf16 bf16_t;
typedef __bf16 bf16x8 __attribute__((ext_vector_type(8)));
typedef float f32x4 __attribute__((ext_vector_type(4)));

// ---------------- preprocessing ----------------

__device__ inline float wave_block_max(float v, float* red) {
  // 64-lane butterfly
  #pragma unroll
  for (int off = 32; off > 0; off >>= 1)
    v = fmaxf(v, __shfl_xor(v, off, 64));
  int lane = threadIdx.x & 63, wid = threadIdx.x >> 6;
  if (lane == 0) red[wid] = v;
  __syncthreads();
  float m = fmaxf(fmaxf(red[0], red[1]), fmaxf(red[2], red[3]));
  return m;
}

// scale_col[n] = max_k |W[n,k]| / 64 ; inv for quantization
__global__ void wscale_kernel(const float* __restrict__ W,
                              float* __restrict__ scale,
                              float* __restrict__ inv_scale) {
  __shared__ float red[4];
  int n = blockIdx.x;
  const float4* row = (const float4*)(W + (size_t)n * K_DIM);
  float amax = 0.f;
  for (int i = threadIdx.x; i < K_DIM / 4; i += blockDim.x) {
    float4 v = row[i];
    amax = fmaxf(amax, fmaxf(fmaxf(fabsf(v.x), fabsf(v.y)),
                             fmaxf(fabsf(v.z), fabsf(v.w))));
  }
  float m = wave_block_max(amax, red);
  if (threadIdx.x == 0) {
    float s = m * (1.0f / 64.0f);
    scale[n] = s;
    inv_scale[n] = (s > 0.f) ? 1.0f / s : 0.f;
  }
}

// col_mask[k] = 1 if any row has |x[m,k]| > sigma  (benign-race stores of 1)
__global__ void colmask_kernel(const float* __restrict__ x,
                               const float* __restrict__ sigma,
                               int* __restrict__ mask, long total4) {
  long i = (long)blockIdx.x * blockDim.x + threadIdx.x;
  if (i >= total4) return;
  float sig = sigma[0];
  float4 v = ((const float4*)x)[i];
  int k = (int)((i * 4) % K_DIM);
  if (fabsf(v.x) > sig) mask[k + 0] = 1;
  if (fabsf(v.y) > sig) mask[k + 1] = 1;
  if (fabsf(v.z) > sig) mask[k + 2] = 1;
  if (fabsf(v.w) > sig) mask[k + 3] = 1;
}

// x_scale[m] = max(max_{k inlier} |x[m,k]| / 127, 1e-8)
__global__ void xscale_kernel(const float* __restrict__ x,
                              const int* __restrict__ mask,
                              float* __restrict__ xs,
                              float* __restrict__ inv_xs) {
  __shared__ float red[4];
  int m = blockIdx.x;
  const float4* row = (const float4*)(x + (size_t)m * K_DIM);
  const int4* mk = (const int4*)mask;
  float amax = 0.f;
  for (int i = threadIdx.x; i < K_DIM / 4; i += blockDim.x) {
    float4 v = row[i];
    int4 b = mk[i];
    if (!b.x) amax = fmaxf(amax, fabsf(v.x));
    if (!b.y) amax = fmaxf(amax, fabsf(v.y));
    if (!b.z) amax = fmaxf(amax, fabsf(v.z));
    if (!b.w) amax = fmaxf(amax, fabsf(v.w));
  }
  float mx = wave_block_max(amax, red);
  if (threadIdx.x == 0) {
    float s = fmaxf(mx * (1.0f / 127.0f), 1e-8f);
    xs[m] = s;
    inv_xs[m] = 1.0f / s;
  }
}

// Qw[n,k] = (bf16) rint(W[n,k] * inv_scale_col[n])   (full matrix, not masked)
__global__ void quantw_kernel(const float* __restrict__ W,
                              const float* __restrict__ inv_scale,
                              bf16_t* __restrict__ Wq, long total8) {
  long i = (long)blockIdx.x * blockDim.x + threadIdx.x;
  if (i >= total8) return;
  size_t e = (size_t)i * 8;
  int n = (int)(e / K_DIM);
  float is = inv_scale[n];
  float4 a = ((const float4*)W)[(size_t)i * 2];
  float4 b = ((const float4*)W)[(size_t)i * 2 + 1];
  bf16x8 q;
  q[0] = (bf16_t)rintf(a.x * is);
  q[1] = (bf16_t)rintf(a.y * is);
  q[2] = (bf16_t)rintf(a.z * is);
  q[3] = (bf16_t)rintf(a.w * is);
  q[4] = (bf16_t)rintf(b.x * is);
  q[5] = (bf16_t)rintf(b.y * is);
  q[6] = (bf16_t)rintf(b.z * is);
  q[7] = (bf16_t)rintf(b.w * is);
  *(bf16x8*)(Wq + e) = q;
}

// A[m,k] = mask[k] ? bf16(x*inv_xs) : bf16(rint(x*inv_xs))
__global__ void quantx_kernel(const float* __restrict__ x,
                              const int* __restrict__ mask,
                              const float* __restrict__ inv_xs,
                              bf16_t* __restrict__ Aq, long total8) {
  long i = (long)blockIdx.x * blockDim.x + threadIdx.x;
  if (i >= total8) return;
  size_t e = (size_t)i * 8;
  int m = (int)(e / K_DIM);
  int k = (int)(e % K_DIM);
  float iv = inv_xs[m];
  float4 a = ((const float4*)x)[(size_t)i * 2];
  float4 b = ((const float4*)x)[(size_t)i * 2 + 1];
  int4 ma = ((const int4*)(mask + k))[0];
  int4 mb = ((const int4*)(mask + k))[1];
  float f[8] = {a.x * iv, a.y * iv, a.z * iv, a.w * iv,
                b.x * iv, b.y * iv, b.z * iv, b.w * iv};
  int  mm[8] = {ma.x, ma.y, ma.z, ma.w, mb.x, mb.y, mb.z, mb.w};
  bf16x8 q;
  #pragma unroll
  for (int j = 0; j < 8; j++)
    q[j] = (bf16_t)(mm[j] ? f[j] : rintf(f[j]));
  *(bf16x8*)(Aq + e) = q;
}

// ---------------- GEMM: out[m,n] = xs[m]*sc[n] * sum_k A[m,k]*Wq[n,k] ----------------

__global__ __launch_bounds__(256) void gemm_kernel(
    const bf16_t* __restrict__ A, const bf16_t* __restrict__ B,
    const float* __restrict__ xs, const float* __restrict__ sc,
    float* __restrict__ out, int M, int N) {
  __shared__ __align__(16) bf16_t As[BM * LDK];
  __shared__ __align__(16) bf16_t Bs[BN * LDK];

  const int bm = blockIdx.y * BM;
  const int bn = blockIdx.x * BN;
  const int t = threadIdx.x;
  const int lane = t & 63;
  const int wave = t >> 6;          // 0..3
  const int wm = (wave & 1) * 64;   // wave sub-tile origin
  const int wn = (wave >> 1) * 64;
  const int l15 = lane & 15;
  const int quad = lane >> 4;       // 0..3

  f32x4 acc[4][4];
  #pragma unroll
  for (int ti = 0; ti < 4; ti++)
    #pragma unroll
    for (int tj = 0; tj < 4; tj++)
      #pragma unroll
      for (int e = 0; e < 4; e++) acc[ti][tj][e] = 0.f;

  // staging: thread t loads 8 bf16 (16B) from 2 rows of each tile
  const int srow = t >> 2;          // 0..63
  const int scol = (t & 3) * 8;     // 0,8,16,24
  const bf16_t* Aptr = A + (size_t)(bm + srow) * K_DIM + scol;
  const bf16_t* Bptr = B + (size_t)(bn + srow) * K_DIM + scol;
  const size_t rstep = (size_t)64 * K_DIM;
  const int ld0 = srow * LDK + scol;
  const int ld1 = (srow + 64) * LDK + scol;

  for (int k0 = 0; k0 < K_DIM; k0 += BK) {
    int4 a0 = *(const int4*)(Aptr + k0);
    int4 a1 = *(const int4*)(Aptr + k0 + rstep);
    int4 b0 = *(const int4*)(Bptr + k0);
    int4 b1 = *(const int4*)(Bptr + k0 + rstep);
    *(int4*)(As + ld0) = a0;
    *(int4*)(As + ld1) = a1;
    *(int4*)(Bs + ld0) = b0;
    *(int4*)(Bs + ld1) = b1;
    __syncthreads();

    bf16x8 af[4], bf[4];
    #pragma unroll
    for (int ti = 0; ti < 4; ti++)
      af[ti] = *(const bf16x8*)(As + (wm + ti * 16 + l15) * LDK + quad * 8);
    #pragma unroll
    for (int tj = 0; tj < 4; tj++)
      bf[tj] = *(const bf16x8*)(Bs + (wn + tj * 16 + l15) * LDK + quad * 8);

    #pragma unroll
    for (int ti = 0; ti < 4; ti++)
      #pragma unroll
      for (int tj = 0; tj < 4; tj++)
        acc[ti][tj] = __builtin_amdgcn_mfma_f32_16x16x32_bf16(
            af[ti], bf[tj], acc[ti][tj], 0, 0, 0);
    __syncthreads();
  }

  // epilogue: C/D layout col=lane&15, row=quad*4+reg
  #pragma unroll
  for (int ti = 0; ti < 4; ti++) {
    #pragma unroll
    for (int i = 0; i < 4; i++) {
      int row = bm + wm + ti * 16 + quad * 4 + i;
      float s_row = xs[row];
      #pragma unroll
      for (int tj = 0; tj < 4; tj++) {
        int col = bn + wn + tj * 16 + l15;
        out[(size_t)row * N + col] = acc[ti][tj][i] * s_row * sc[col];
      }
    }
  }
}

// ---------------- launch ----------------

extern "C" void kernel_launch(void* const* d_in, const int* in_sizes, int n_in,
                              void* d_out, int out_size, void* d_ws, size_t ws_size,
                              hipStream_t stream) {
  const float* x = (const float*)d_in[0];
  const float* W = (const float*)d_in[1];
  const float* sigma = (const float*)d_in[2];
  float* out = (float*)d_out;

  const int K = K_DIM;
  const int M = in_sizes[0] / K;  // 8192
  const int N = in_sizes[1] / K;  // 11008

  char* ws = (char*)d_ws;
  size_t off = 0;
  auto alloc = [&](size_t bytes) -> void* {
    void* p = ws + off;
    off += (bytes + 255) & ~(size_t)255;
    return p;
  };
  float* scale_col     = (float*)alloc((size_t)N * 4);
  float* inv_scale_col = (float*)alloc((size_t)N * 4);
  int*   mask          = (int*)alloc((size_t)K * 4);
  float* xs            = (float*)alloc((size_t)M * 4);
  float* inv_xs        = (float*)alloc((size_t)M * 4);
  bf16_t* Wq           = (bf16_t*)alloc((size_t)N * K * 2);
  bf16_t* Aq           = (bf16_t*)alloc((size_t)M * K * 2);

  hipMemsetAsync(mask, 0, (size_t)K * sizeof(int), stream);

  wscale_kernel<<<N, 256, 0, stream>>>(W, scale_col, inv_scale_col);

  long total4 = (long)M * K / 4;
  colmask_kernel<<<(int)((total4 + 255) / 256), 256, 0, stream>>>(x, sigma, mask, total4);

  xscale_kernel<<<M, 256, 0, stream>>>(x, mask, xs, inv_xs);

  long wq8 = (long)N * K / 8;
  quantw_kernel<<<(int)((wq8 + 255) / 256), 256, 0, stream>>>(W, inv_scale_col, Wq, wq8);

  long xq8 = (long)M * K / 8;
  quantx_kernel<<<(int)((xq8 + 255) / 256), 256, 0, stream>>>(x, mask, inv_xs, Aq, xq8);

  dim3 grid(N / BN, M / BM);  // (86, 64)
  gemm_kernel<<<grid, 256, 0, stream>>>(Aq, Wq, xs, scale_col, out, M, N);
}

// Round 2
// 1645.566 us; speedup vs baseline: 1.1159x; 1.1159x over previous
//
#include <hip/hip_runtime.h>
#include <hip/hip_bf16.h>
#include <stdint.h>

#define K_DIM 4096
#define BM 128
#define BN 128
#define BK 32

typedef __bf16 bf16_t;
typedef __bf16 bf16x8 __attribute__((ext_vector_type(8)));
typedef __bf16 bf16x4 __attribute__((ext_vector_type(4)));
typedef float f32x4 __attribute__((ext_vector_type(4)));

// async global->LDS, 16B per lane. LDS dest = wave-uniform base + lane*16B.
__device__ inline void async16(const bf16_t* g, bf16_t* l) {
  __builtin_amdgcn_global_load_lds(
      (const __attribute__((address_space(1))) void*)g,
      (__attribute__((address_space(3))) void*)l, 16, 0, 0);
}

// ---------------- preprocessing ----------------

__device__ inline float wave_block_max(float v, float* red) {
  #pragma unroll
  for (int off = 32; off > 0; off >>= 1)
    v = fmaxf(v, __shfl_xor(v, off, 64));
  int lane = threadIdx.x & 63, wid = threadIdx.x >> 6;
  if (lane == 0) red[wid] = v;
  __syncthreads();
  return fmaxf(fmaxf(red[0], red[1]), fmaxf(red[2], red[3]));
}

// col_mask[k] = 1 if any row has |x[m,k]| > sigma  (benign-race stores of 1)
__global__ void colmask_kernel(const float* __restrict__ x,
                               const float* __restrict__ sigma,
                               int* __restrict__ mask, long total4) {
  long i = (long)blockIdx.x * blockDim.x + threadIdx.x;
  if (i >= total4) return;
  float sig = sigma[0];
  float4 v = ((const float4*)x)[i];
  int k = (int)((i * 4) % K_DIM);
  if (fabsf(v.x) > sig) mask[k + 0] = 1;
  if (fabsf(v.y) > sig) mask[k + 1] = 1;
  if (fabsf(v.z) > sig) mask[k + 2] = 1;
  if (fabsf(v.w) > sig) mask[k + 3] = 1;
}

// per weight-row n: scale_col[n] = max|W[n,:]|/64; Wq[n,k] = bf16(rint(W*inv))
__global__ __launch_bounds__(256) void fused_w_kernel(
    const float* __restrict__ W, float* __restrict__ scale,
    bf16_t* __restrict__ Wq) {
  __shared__ float red[4];
  int n = blockIdx.x;
  const float4* row = (const float4*)(W + (size_t)n * K_DIM);
  float4 v[4];
  float amax = 0.f;
  #pragma unroll
  for (int j = 0; j < 4; j++) {
    v[j] = row[threadIdx.x + j * 256];
    amax = fmaxf(amax, fmaxf(fmaxf(fabsf(v[j].x), fabsf(v[j].y)),
                             fmaxf(fabsf(v[j].z), fabsf(v[j].w))));
  }
  float mx = wave_block_max(amax, red);
  float s = mx * (1.0f / 64.0f);
  if (threadIdx.x == 0) scale[n] = s;
  float is = (s > 0.f) ? 1.0f / s : 0.f;
  bf16_t* orow = Wq + (size_t)n * K_DIM;
  #pragma unroll
  for (int j = 0; j < 4; j++) {
    bf16x4 q;
    q[0] = (bf16_t)rintf(v[j].x * is);
    q[1] = (bf16_t)rintf(v[j].y * is);
    q[2] = (bf16_t)rintf(v[j].z * is);
    q[3] = (bf16_t)rintf(v[j].w * is);
    *(bf16x4*)(orow + (size_t)(threadIdx.x + j * 256) * 4) = q;
  }
}

// per activation-row m: xs[m] = max(max inlier|x|/127, 1e-8);
// Aq[m,k] = mask ? bf16(x*inv) : bf16(rint(x*inv))
__global__ __launch_bounds__(256) void fused_x_kernel(
    const float* __restrict__ x, const int* __restrict__ mask,
    float* __restrict__ xs, bf16_t* __restrict__ Aq) {
  __shared__ float red[4];
  int m = blockIdx.x;
  const float4* row = (const float4*)(x + (size_t)m * K_DIM);
  const int4* mk = (const int4*)mask;
  float4 v[4];
  int4 b[4];
  float amax = 0.f;
  #pragma unroll
  for (int j = 0; j < 4; j++) {
    v[j] = row[threadIdx.x + j * 256];
    b[j] = mk[threadIdx.x + j * 256];
    if (!b[j].x) amax = fmaxf(amax, fabsf(v[j].x));
    if (!b[j].y) amax = fmaxf(amax, fabsf(v[j].y));
    if (!b[j].z) amax = fmaxf(amax, fabsf(v[j].z));
    if (!b[j].w) amax = fmaxf(amax, fabsf(v[j].w));
  }
  float mx = wave_block_max(amax, red);
  float s = fmaxf(mx * (1.0f / 127.0f), 1e-8f);
  if (threadIdx.x == 0) xs[m] = s;
  float iv = 1.0f / s;
  bf16_t* orow = Aq + (size_t)m * K_DIM;
  #pragma unroll
  for (int j = 0; j < 4; j++) {
    float f0 = v[j].x * iv, f1 = v[j].y * iv, f2 = v[j].z * iv, f3 = v[j].w * iv;
    bf16x4 q;
    q[0] = (bf16_t)(b[j].x ? f0 : rintf(f0));
    q[1] = (bf16_t)(b[j].y ? f1 : rintf(f1));
    q[2] = (bf16_t)(b[j].z ? f2 : rintf(f2));
    q[3] = (bf16_t)(b[j].w ? f3 : rintf(f3));
    *(bf16x4*)(orow + (size_t)(threadIdx.x + j * 256) * 4) = q;
  }
}

// ---------------- GEMM: out[m,n] = xs[m]*sc[n] * sum_k A[m,k]*Wq[n,k] ----------------
// m97 structure: global_load_lds width=16, unpadded 128x32 LDS tiles.

__global__ __launch_bounds__(256) void gemm_kernel(
    const bf16_t* __restrict__ A, const bf16_t* __restrict__ B,
    const float* __restrict__ xs, const float* __restrict__ sc,
    float* __restrict__ out, int M, int N) {
  __shared__ __align__(16) bf16_t As[BM * BK];  // 8 KiB, row-major stride 32
  __shared__ __align__(16) bf16_t Bs[BN * BK];

  const int bm = blockIdx.y * BM;
  const int bn = blockIdx.x * BN;
  const int t = threadIdx.x;
  const int lane = t & 63;
  const int wave = t >> 6;          // 0..3
  const int wm = (wave & 1) * 64;
  const int wn = (wave >> 1) * 64;
  const int l15 = lane & 15;
  const int quad = lane >> 4;       // 0..3

  f32x4 acc[4][4];
  #pragma unroll
  for (int ti = 0; ti < 4; ti++)
    #pragma unroll
    for (int tj = 0; tj < 4; tj++)
      #pragma unroll
      for (int e = 0; e < 4; e++) acc[ti][tj][e] = 0.f;

  // staging: wave w lane l -> tile row w*16 + (l>>2), cols (l&3)*8 .. +8 (16B)
  // LDS: row-major stride 32 elems; wave base = w*16*32 elems = w*1024 B;
  // HW writes at base + lane*16B == (w*16 + l>>2)*64B + (l&3)*16B  (matches)
  const int g_row = wave * 16 + (lane >> 2);
  const int g_col = (lane & 3) * 8;
  const bf16_t* Ap = A + (size_t)(bm + g_row) * K_DIM + g_col;
  const bf16_t* Bp = B + (size_t)(bn + g_row) * K_DIM + g_col;
  const size_t rstep = (size_t)64 * K_DIM;
  bf16_t* As0 = As + wave * 512;    // elements
  bf16_t* Bs0 = Bs + wave * 512;

  for (int k0 = 0; k0 < K_DIM; k0 += BK) {
    async16(Ap + k0,         As0);
    async16(Ap + k0 + rstep, As0 + 64 * BK);
    async16(Bp + k0,         Bs0);
    async16(Bp + k0 + rstep, Bs0 + 64 * BK);
    __syncthreads();   // compiler emits vmcnt(0) drain here (m97 behavior)

    bf16x8 af[4], bfr[4];
    #pragma unroll
    for (int ti = 0; ti < 4; ti++)
      af[ti] = *(const bf16x8*)(As + (wm + ti * 16 + l15) * BK + quad * 8);
    #pragma unroll
    for (int tj = 0; tj < 4; tj++)
      bfr[tj] = *(const bf16x8*)(Bs + (wn + tj * 16 + l15) * BK + quad * 8);

    #pragma unroll
    for (int ti = 0; ti < 4; ti++)
      #pragma unroll
      for (int tj = 0; tj < 4; tj++)
        acc[ti][tj] = __builtin_amdgcn_mfma_f32_16x16x32_bf16(
            af[ti], bfr[tj], acc[ti][tj], 0, 0, 0);
    __syncthreads();
  }

  // epilogue: C/D layout col=lane&15, row=quad*4+reg
  #pragma unroll
  for (int ti = 0; ti < 4; ti++) {
    #pragma unroll
    for (int i = 0; i < 4; i++) {
      int row = bm + wm + ti * 16 + quad * 4 + i;
      float s_row = xs[row];
      #pragma unroll
      for (int tj = 0; tj < 4; tj++) {
        int col = bn + wn + tj * 16 + l15;
        out[(size_t)row * N + col] = acc[ti][tj][i] * s_row * sc[col];
      }
    }
  }
}

// ---------------- launch ----------------

extern "C" void kernel_launch(void* const* d_in, const int* in_sizes, int n_in,
                              void* d_out, int out_size, void* d_ws, size_t ws_size,
                              hipStream_t stream) {
  const float* x = (const float*)d_in[0];
  const float* W = (const float*)d_in[1];
  const float* sigma = (const float*)d_in[2];
  float* out = (float*)d_out;

  const int K = K_DIM;
  const int M = in_sizes[0] / K;  // 8192
  const int N = in_sizes[1] / K;  // 11008

  char* ws = (char*)d_ws;
  size_t off = 0;
  auto alloc = [&](size_t bytes) -> void* {
    void* p = ws + off;
    off += (bytes + 255) & ~(size_t)255;
    return p;
  };
  float* scale_col = (float*)alloc((size_t)N * 4);
  int*   mask      = (int*)alloc((size_t)K * 4);
  float* xs        = (float*)alloc((size_t)M * 4);
  bf16_t* Wq       = (bf16_t*)alloc((size_t)N * K * 2);
  bf16_t* Aq       = (bf16_t*)alloc((size_t)M * K * 2);

  hipMemsetAsync(mask, 0, (size_t)K * sizeof(int), stream);

  long total4 = (long)M * K / 4;
  colmask_kernel<<<(int)((total4 + 255) / 256), 256, 0, stream>>>(x, sigma, mask, total4);

  fused_w_kernel<<<N, 256, 0, stream>>>(W, scale_col, Wq);
  fused_x_kernel<<<M, 256, 0, stream>>>(x, mask, xs, Aq);

  dim3 grid(N / BN, M / BM);  // (86, 64)
  gemm_kernel<<<grid, 256, 0, stream>>>(Aq, Wq, xs, scale_col, out, M, N);
}